// Round 1
// 274.456 us; speedup vs baseline: 1.0243x; 1.0243x over previous
//
#include <hip/hip_runtime.h>
#include <stdint.h>

#define DEVI __device__ __forceinline__

typedef unsigned short ushort_t;
typedef __bf16 bf16x8 __attribute__((ext_vector_type(8)));
typedef float f32x4 __attribute__((ext_vector_type(4)));
typedef unsigned short ushort8 __attribute__((ext_vector_type(8)));
typedef short s16x4 __attribute__((ext_vector_type(4)));

// ---- constants ----
#define BB 4
#define TT 2048
#define CC 1024
#define NH 16
#define HD 64
#define MM (BB*TT)          // 8192

DEVI ushort_t f2bf(float f) {
    union { float f; unsigned u; } v; v.f = f;
    return (ushort_t)((v.u + 0x7FFFu + ((v.u >> 16) & 1u)) >> 16);
}

typedef const __attribute__((address_space(1))) unsigned int guint_t;
typedef __attribute__((address_space(3))) unsigned int luint_t;

// async global->LDS, 16B/lane; lds dest is wave-uniform base + lane*16
DEVI void gl2lds16(const void* g, void* lds) {
    __builtin_amdgcn_global_load_lds((guint_t*)(uintptr_t)g,
                                     (luint_t*)(unsigned int)(uintptr_t)lds,
                                     16, 0, 0);
}

template <int N> DEVI void waitvm() {
    static_assert(N == 0 || N == 6 || N == 8, "unsupported vmcnt literal");
    if constexpr (N == 0)      asm volatile("s_waitcnt vmcnt(0)" ::: "memory");
    else if constexpr (N == 6) asm volatile("s_waitcnt vmcnt(6)" ::: "memory");
    else if constexpr (N == 8) asm volatile("s_waitcnt vmcnt(8)" ::: "memory");
}

// ---------------- fp32 -> bf16 bulk convert (8 elems/thread) ----------------
__global__ void cvt_f32_bf16(const float* __restrict__ in,
                             ushort_t* __restrict__ out) {
    int i = blockIdx.x * 256 + threadIdx.x;
    const float4* p = (const float4*)in + (size_t)i * 2;
    float4 a = p[0], b = p[1];
    ushort8 r;
    r[0] = f2bf(a.x); r[1] = f2bf(a.y); r[2] = f2bf(a.z); r[3] = f2bf(a.w);
    r[4] = f2bf(b.x); r[5] = f2bf(b.y); r[6] = f2bf(b.z); r[7] = f2bf(b.w);
    *(ushort8*)(out + (size_t)i * 8) = r;
}

// ------------- transpose fp32 -> bf16: in[R][Cc] -> out[Cc][R] -------------
__global__ void transpose_f2b(const float* __restrict__ in,
                              ushort_t* __restrict__ out, int R, int Cc) {
    __shared__ ushort_t tile[32][33];
    int bx = blockIdx.x * 32;
    int by = blockIdx.y * 32;
    int tx = threadIdx.x & 31, ty = threadIdx.x >> 5;
    #pragma unroll
    for (int i = 0; i < 4; i++) {
        int r = ty * 4 + i;
        tile[r][tx] = f2bf(in[(size_t)(by + r) * Cc + bx + tx]);
    }
    __syncthreads();
    #pragma unroll
    for (int i = 0; i < 4; i++) {
        int r = ty * 4 + i;
        out[(size_t)(bx + r) * R + by + tx] = tile[tx][r];
    }
}

// ---------------- rope table: tab[t*32+j] = (cos, sin) ----------------
__global__ void rope_table(float2* __restrict__ tab) {
    int i = blockIdx.x * 256 + threadIdx.x;   // 65536 total
    int t = i >> 5, j = i & 31;
    float inv = exp2f((float)j * -0.41524101186092029f);
    float theta = (float)t * inv;
    float s, c;
    sincosf(theta, &s, &c);
    tab[i] = make_float2(c, s);
}

// ------- V transpose: Vb[bh][t][d] -> VbT[bh][d][t], 64x64 tiles -------
__global__ void vtrans(const ushort_t* __restrict__ Vb,
                       ushort_t* __restrict__ VbT) {
    __shared__ ushort_t tile[64 * 72];
    const int bh = blockIdx.y;
    const int t0 = blockIdx.x * 64;
    const int tid = threadIdx.x;
    const int r = tid >> 2, c = (tid & 3) * 16;
    const size_t base = (size_t)bh * (TT * HD);
    const ushort_t* g = Vb + base + (size_t)(t0 + r) * HD + c;
    *(ushort8*)&tile[r * 72 + c]     = *(const ushort8*)g;
    *(ushort8*)&tile[r * 72 + c + 8] = *(const ushort8*)(g + 8);
    __syncthreads();
    ushort8 a, b;
    #pragma unroll
    for (int j = 0; j < 8; j++) a[j] = tile[(c + j) * 72 + r];
    #pragma unroll
    for (int j = 0; j < 8; j++) b[j] = tile[(c + 8 + j) * 72 + r];
    ushort_t* o = VbT + base + (size_t)r * TT + t0 + c;
    *(ushort8*)o = a;
    *(ushort8*)(o + 8) = b;
}

// ---------------- GEMM: C = A * Bt^T  (A,Bt bf16) --------------------------
// 128x256 tile, BK=64, 512 threads = 8 waves (2M x 4N), double-buffered LDS,
// counted vmcnt (T3+T4), XOR-swizzled LDS via pre-swizzled global source
// (T2, rule-21 both-sides), setprio around MFMA cluster (T5), XCD-bijective
// block swizzle (T1).
// MODE 1: A=[M][Kd] row-major; qkv epilogue: rope q,k (q pre-scaled by
//         scale*log2e); scatter to [B*NH][T][HD]
// MODE 2: A head-major [(b*16+h)*2048+t][64]; fp32 store to CoutF[M][N]
template <int MODE, int BM>
__global__ __launch_bounds__(512, 2) void gemm_bt(
    const ushort_t* __restrict__ A, const ushort_t* __restrict__ Bt,
    float* __restrict__ CoutF,
    ushort_t* __restrict__ Qb, ushort_t* __restrict__ Kb, ushort_t* __restrict__ Vb,
    const float2* __restrict__ rope, int M, int N, int Kd) {
    constexpr int MR = BM / 32;      // M fragment repeats per wave (BM/2/16)
    constexpr int AL = BM / 64;      // A gl2lds per wave per K-tile
    constexpr int L  = AL + 4;       // vmem loads per STAGE per thread
    constexpr int NK = CC / 64;      // K-tiles (Kd == 1024 for both GEMMs)
    (void)M;

    __shared__ __attribute__((aligned(16))) ushort_t As[2][BM * 64];
    __shared__ __attribute__((aligned(16))) ushort_t Bs[2][256 * 64];

    const int tid = threadIdx.x;
    const int w = tid >> 6, l = tid & 63;
    const int lane15 = l & 15, quad = l >> 4;
    const int wm = (w >> 2) * (BM / 2);      // wave M offset (0 or BM/2)
    const int wn = (w & 3) * 64;             // wave N offset

    // XCD-aware bijective swizzle (both grids are multiples of 8 blocks)
    const int nbn = gridDim.x;
    const int nwg = nbn * gridDim.y;
    const int lid = blockIdx.y * nbn + blockIdx.x;
    const int sid = (lid & 7) * (nwg >> 3) + (lid >> 3);
    const int bn = sid % nbn, bm = sid / nbn;

    const int sr8 = l >> 3;      // staged row within 8-row block
    const int sc  = l & 7;       // 16B slot within 128B row

    // stage one K-tile (A: BM x 64, B: 256 x 64) into buffer `buf`.
    // LDS dest linear; source column slot XOR'd by row&7 so that a read of
    // LDS[row][cb ^ ((row&7)<<4)] returns G[row][cb]  (involution).
    auto STAGE = [&](int buf, int k0) {
        #pragma unroll
        for (int i = 0; i < AL; ++i) {
            int r = w * (BM / 8) + i * 8 + sr8;       // r&7 == sr8
            int gr = bm * BM + r;
            size_t e;
            if constexpr (MODE == 2)
                e = ((size_t)(gr >> 11)) * 2097152 + ((size_t)(k0 >> 6)) * 131072
                    + (size_t)(gr & (TT - 1)) * 64;
            else
                e = (size_t)gr * Kd + k0;
            const char* g = (const char*)(A + e) + ((sc ^ sr8) * 16);
            gl2lds16(g, (char*)&As[buf][0] + (w * (BM / 8) + i * 8) * 128);
        }
        #pragma unroll
        for (int i = 0; i < 4; ++i) {
            int r = w * 32 + i * 8 + sr8;
            int gr = bn * 256 + r;
            const char* g = (const char*)(Bt + (size_t)gr * Kd + k0)
                            + ((sc ^ sr8) * 16);
            gl2lds16(g, (char*)&Bs[buf][0] + (w * 32 + i * 8) * 128);
        }
    };

    f32x4 acc[MR][4];
    #pragma unroll
    for (int m = 0; m < MR; ++m)
        #pragma unroll
        for (int n = 0; n < 4; ++n)
            acc[m][n] = f32x4{0.f, 0.f, 0.f, 0.f};

    // prologue: tiles 0 and 1 in flight; wait tile 0 only
    STAGE(0, 0);
    STAGE(1, 64);
    waitvm<L>();
    __builtin_amdgcn_s_barrier();
    asm volatile("" ::: "memory");

    const int swz = (lane15 & 7) << 4;   // read-side XOR (row&7 == lane15&7)

    for (int k = 0; k < NK; ++k) {
        const char* Asb = (const char*)&As[k & 1][0];
        const char* Bsb = (const char*)&Bs[k & 1][0];
        #pragma unroll
        for (int kk = 0; kk < 2; ++kk) {
            const int cb = (kk * 64 + quad * 16) ^ swz;
            bf16x8 bfr[4];
            #pragma unroll
            for (int n = 0; n < 4; ++n)
                bfr[n] = *(const bf16x8*)(Bsb + (wn + n * 16 + lane15) * 128 + cb);
            bf16x8 af[MR];
            #pragma unroll
            for (int m = 0; m < MR; ++m)
                af[m] = *(const bf16x8*)(Asb + (wm + m * 16 + lane15) * 128 + cb);
            __builtin_amdgcn_s_setprio(1);
            #pragma unroll
            for (int m = 0; m < MR; ++m)
                #pragma unroll
                for (int n = 0; n < 4; ++n)
                    acc[m][n] = __builtin_amdgcn_mfma_f32_16x16x32_bf16(
                        af[m], bfr[n], acc[m][n], 0, 0, 0);
            __builtin_amdgcn_s_setprio(0);
        }
        if (k == NK - 1) break;

        // release buf[k&1]: MFMAs must not sink past, reads must be retired
        __builtin_amdgcn_sched_barrier(0);
        asm volatile("s_waitcnt lgkmcnt(0)" ::: "memory");
        __builtin_amdgcn_s_barrier();
        asm volatile("" ::: "memory");
        // stage k+2 into just-released buffer; wait k+1 complete (counted,
        // leaves k+2's L loads in flight across the barrier)
        if (k + 2 < NK) { STAGE(k & 1, (k + 2) * 64); waitvm<L>(); }
        else            waitvm<0>();
        __builtin_amdgcn_s_barrier();
        asm volatile("" ::: "memory");
    }

    if constexpr (MODE == 1) {
        const float SCQ = 0.125f * 1.4426950408889634f;   // folded into Q
        const int colbase = bn * 256 + wn;          // multiple of 64
        const int seg = colbase >> 10;              // 0=q 1=k 2=v
        const int h = (colbase & 1023) >> 6;        // head
        #pragma unroll
        for (int m = 0; m < MR; ++m) {
            int row0 = bm * BM + wm + m * 16 + quad * 4;
            #pragma unroll
            for (int r = 0; r < 4; ++r) {
                int row = row0 + r;
                int b = row >> 11, t = row & (TT - 1);
                size_t ob = ((size_t)(b * NH + h) * TT + t) * HD;
                if (seg == 2) {
                    #pragma unroll
                    for (int n = 0; n < 4; ++n)
                        Vb[ob + n * 16 + lane15] = f2bf(acc[m][n][r]);
                } else {
                    ushort_t* dst = (seg == 0) ? Qb : Kb;
                    #pragma unroll
                    for (int n = 0; n < 2; ++n) {
                        int j = n * 16 + lane15;        // 0..31
                        float2 cs = rope[t * 32 + j];
                        float x1 = acc[m][n][r];        // d = j
                        float x2 = acc[m][n + 2][r];    // d = j+32
                        float y1 = x1 * cs.x - x2 * cs.y;
                        float y2 = x2 * cs.x + x1 * cs.y;
                        if (seg == 0) { y1 *= SCQ; y2 *= SCQ; }
                        dst[ob + j]      = f2bf(y1);
                        dst[ob + 32 + j] = f2bf(y2);
                    }
                }
            }
        }
    } else {
        #pragma unroll
        for (int m = 0; m < MR; ++m) {
            #pragma unroll
            for (int r = 0; r < 4; ++r) {
                size_t rb = (size_t)(bm * BM + wm + m * 16 + quad * 4 + r) * N
                            + bn * 256 + wn;
                #pragma unroll
                for (int n = 0; n < 4; ++n)
                    CoutF[rb + n * 16 + lane15] = acc[m][n][r];
            }
        }
    }
}

// ---------------- flash attention (causal), O in place over Q --------------
// grid: (8 qt-pairs, B*NH); block 512 = 8 waves x 16 q-rows. Block handles
// q-tiles {p, 15-p} of 128 rows: exactly 34 k-iterations -> perfect balance.
// S^T = K*Q^T: S^T's C-frag (kcol=quad*4+reg, qrow=lane15) IS the A-operand
// layout of mfma_16x16x16_bf16 -> P never touches LDS. Q pre-scaled by
// scale*log2e in GEMM1, so scores are already in the exp2 domain.
__global__ __launch_bounds__(512, 4) void attn_kernel(
    ushort_t* __restrict__ Qb, const ushort_t* __restrict__ Kb,
    const ushort_t* __restrict__ VbT) {
    __shared__ __attribute__((aligned(16))) ushort_t Ks[64 * 72];   // K tile [t][d]
    __shared__ __attribute__((aligned(16))) ushort_t Vs[64 * 72];   // V^T tile [d][t]

    const int tid = threadIdx.x;
    const int w = tid >> 6, l = tid & 63;
    const int lane15 = l & 15, quad = l >> 4;
    const int bh = blockIdx.y;
    const size_t base = (size_t)bh * (TT * HD);

    const int sr = tid >> 3;         // staging row 0..63
    const int sd = (tid & 7) * 8;    // staging col (elems), 16B per thread
    const ushort_t* kgb = Kb  + base + (size_t)sr * HD + sd;   // + kt*64*HD
    const ushort_t* vgb = VbT + base + (size_t)sr * TT + sd;   // + kt*64

    #pragma unroll
    for (int seg = 0; seg < 2; seg++) {
        const int qt = (seg == 0) ? (int)blockIdx.x : (15 - (int)blockIdx.x);
        const int q0 = qt * 128;
        const int rbase = q0 + w * 16;     // wave owns 16 q-rows
        const int ktmax = 2 * qt + 1;

        // Q fragments (B-operand of S^T: n=lane15->qrow, k=quad*8+j->dim)
        bf16x8 qf0, qf1;
        {
            const ushort_t* qp = Qb + base + (size_t)(rbase + lane15) * HD + quad * 8;
            qf0 = *(const bf16x8*)qp;
            qf1 = *(const bf16x8*)(qp + 32);
        }

        f32x4 o[4];
        #pragma unroll
        for (int nt = 0; nt < 4; nt++) o[nt] = f32x4{0.f, 0.f, 0.f, 0.f};
        float mrow = -INFINITY, lrow = 0.f;   // per qrow=lane15

        // prefetch tile 0 of this segment
        ushort8 kr = *(const ushort8*)kgb;
        ushort8 vr = *(const ushort8*)vgb;

        for (int kt = 0; kt <= ktmax; kt++) {
            __syncthreads();   // prior iter's LDS readers done
            *(ushort8*)&Ks[sr * 72 + sd] = kr;
            *(ushort8*)&Vs[sr * 72 + sd] = vr;
            __syncthreads();
            if (kt < ktmax) {   // prefetch next tile; overlaps compute
                kr = *(const ushort8*)(kgb + (size_t)(kt + 1) * 64 * HD);
                vr = *(const ushort8*)(vgb + (size_t)(kt + 1) * 64);
            }

            // S^T tiles: D[kcol][qrow], kcol=c*16+quad*4+reg, qrow=lane15
            f32x4 s[4];
            #pragma unroll
            for (int c = 0; c < 4; c++) {
                bf16x8 k0 = *(const bf16x8*)&Ks[(c * 16 + lane15) * 72 + quad * 8];
                bf16x8 k1 = *(const bf16x8*)&Ks[(c * 16 + lane15) * 72 + 32 + quad * 8];
                f32x4 z = f32x4{0.f, 0.f, 0.f, 0.f};
                z = __builtin_amdgcn_mfma_f32_16x16x32_bf16(k0, qf0, z, 0, 0, 0);
                s[c] = __builtin_amdgcn_mfma_f32_16x16x32_bf16(k1, qf1, z, 0, 0, 0);
            }

            const int qrow = rbase + lane15;
            if (kt * 64 + 63 > rbase) {   // masking needed (wave-uniform)
                #pragma unroll
                for (int c = 0; c < 4; c++)
                    #pragma unroll
                    for (int r = 0; r < 4; r++)
                        if (kt * 64 + c * 16 + quad * 4 + r > qrow) s[c][r] = -1e9f;
            }

            // per-qrow max: 16 in-lane + cross-quad (2 shuffles)
            float mt = s[0][0];
            #pragma unroll
            for (int c = 0; c < 4; c++)
                #pragma unroll
                for (int r = 0; r < 4; r++) mt = fmaxf(mt, s[c][r]);
            mt = fmaxf(mt, __shfl_xor(mt, 16, 64));
            mt = fmaxf(mt, __shfl_xor(mt, 32, 64));

            float mn = fmaxf(mrow, mt);
            float alpha = __builtin_amdgcn_exp2f(mrow - mn);
            mrow = mn;

            #pragma unroll
            for (int c = 0; c < 4; c++)
                #pragma unroll
                for (int r = 0; r < 4; r++)
                    s[c][r] = __builtin_amdgcn_exp2f(s[c][r] - mn);

            float rs = 0.f;
            #pragma unroll
            for (int c = 0; c < 4; c++)
                rs += (s[c][0] + s[c][1]) + (s[c][2] + s[c][3]);
            rs += __shfl_xor(rs, 16, 64);
            rs += __shfl_xor(rs, 32, 64);
            lrow = lrow * alpha + rs;

            // alpha lives in lane=qrow (replicated across quads); o rows are
            // qrow = rbase + quad*4 + r -> broadcast from lane quad*4+r
            #pragma unroll
            for (int r = 0; r < 4; r++) {
                float aO = __shfl(alpha, quad * 4 + r, 64);
                #pragma unroll
                for (int nt = 0; nt < 4; nt++) o[nt][r] *= aO;
            }

            // P A-frags (m=lane15->qrow, k=quad*4+j->kcol) == S^T C-frag
            #pragma unroll
            for (int c = 0; c < 4; c++) {
                s16x4 pf;
                #pragma unroll
                for (int r = 0; r < 4; r++) pf[r] = (short)f2bf(s[c][r]);
                #pragma unroll
                for (int nt = 0; nt < 4; nt++) {
                    s16x4 vf = *(const s16x4*)&Vs[(nt * 16 + lane15) * 72 +
                                                  c * 16 + quad * 4];
                    o[nt] = __builtin_amdgcn_mfma_f32_16x16x16bf16_1k(
                        pf, vf, o[nt], 0, 0, 0);
                }
            }
        }

        // epilogue: O in place over this wave's Q rows (head-major)
        float linv = 1.0f / lrow;   // lane=qrow domain
        #pragma unroll
        for (int r = 0; r < 4; r++) {
            float lO = __shfl(linv, quad * 4 + r, 64);
            size_t rb = base + (size_t)(rbase + quad * 4 + r) * HD;
            #pragma unroll
            for (int nt = 0; nt < 4; nt++)
                Qb[rb + nt * 16 + lane15] = f2bf(o[nt][r] * lO);
        }
    }
}

// ---------------- launch ----------------
extern "C" void kernel_launch(void* const* d_in, const int* in_sizes, int n_in,
                              void* d_out, int out_size, void* d_ws, size_t ws_size,
                              hipStream_t stream) {
    const float* x    = (const float*)d_in[0];   // [8192][1024] fp32
    const float* wqkv = (const float*)d_in[1];   // [1024][3072] fp32
    const float* wout = (const float*)d_in[2];   // [1024][1024] fp32
    float* out = (float*)d_out;                  // [8192][1024] fp32

    // ws layout (72.5 MiB total):
    char* ws = (char*)d_ws;
    ushort_t* WqkvT = (ushort_t*)(ws);                        // [3072][1024] bf16
    ushort_t* WoutT = (ushort_t*)(ws + 6291456);              // [1024][1024] bf16
    float2*   rope  = (float2*)  (ws + 8388608);              // [2048*32]
    ushort_t* Xb    = (ushort_t*)(ws + 8912896);              // [8192][1024] bf16
    ushort_t* Qb    = (ushort_t*)(ws + 8912896 + 16777216);   // [64][2048][64]
    ushort_t* Kb    = (ushort_t*)(ws + 8912896 + 2 * 16777216);
    ushort_t* Vb    = (ushort_t*)(ws + 8912896 + 3 * 16777216);
    // VbT aliases Xb: Xb is dead after GEMM1, VbT produced after GEMM1.
    ushort_t* VbT   = Xb;                                     // [64][64][2048]

    cvt_f32_bf16<<<dim3(MM * CC / (256 * 8)), 256, 0, stream>>>(x, Xb);
    transpose_f2b<<<dim3(3 * CC / 32, CC / 32), 256, 0, stream>>>(wqkv, WqkvT, CC, 3 * CC);
    transpose_f2b<<<dim3(CC / 32, CC / 32), 256, 0, stream>>>(wout, WoutT, CC, CC);
    rope_table<<<dim3(256), 256, 0, stream>>>(rope);

    // 128x256 tiles: grid1 = 12x64 = 768 blocks (3 exact CU-rounds),
    // grid2 = 4x64 = 256 blocks (1 exact round); both %8==0 for XCD swizzle.
    gemm_bt<1, 128><<<dim3(3 * CC / 256, MM / 128), 512, 0, stream>>>(
        Xb, WqkvT, nullptr, Qb, Kb, Vb, rope, MM, 3 * CC, CC);

    vtrans<<<dim3(TT / 64, BB * NH), 256, 0, stream>>>(Vb, VbT);

    attn_kernel<<<dim3(8, BB * NH), 512, 0, stream>>>(Qb, Kb, VbT);

    gemm_bt<2, 128><<<dim3(CC / 256, MM / 128), 512, 0, stream>>>(
        Qb, WoutT, out, nullptr, nullptr, nullptr, nullptr, MM, CC, CC);
}

// Round 2
// 270.814 us; speedup vs baseline: 1.0381x; 1.0134x over previous
//
#include <hip/hip_runtime.h>
#include <stdint.h>

#define DEVI __device__ __forceinline__

typedef unsigned short ushort_t;
typedef __bf16 bf16x8 __attribute__((ext_vector_type(8)));
typedef float f32x4 __attribute__((ext_vector_type(4)));
typedef unsigned short ushort8 __attribute__((ext_vector_type(8)));
typedef short s16x4 __attribute__((ext_vector_type(4)));

// ---- constants ----
#define BB 4
#define TT 2048
#define CC 1024
#define NH 16
#define HD 64
#define MM (BB*TT)          // 8192

// native RNE f32->bf16 (compiler pairs into v_cvt_pk_bf16_f32; m240)
DEVI ushort_t f2bf(float f) {
    __bf16 h = (__bf16)f;
    return __builtin_bit_cast(ushort_t, h);
}

typedef const __attribute__((address_space(1))) unsigned int guint_t;
typedef __attribute__((address_space(3))) unsigned int luint_t;

// async global->LDS, 16B/lane; lds dest is wave-uniform base + lane*16
DEVI void gl2lds16(const void* g, void* lds) {
    __builtin_amdgcn_global_load_lds((guint_t*)(uintptr_t)g,
                                     (luint_t*)(unsigned int)(uintptr_t)lds,
                                     16, 0, 0);
}

template <int N> DEVI void waitvm() {
    static_assert(N == 0 || N == 6 || N == 8, "unsupported vmcnt literal");
    if constexpr (N == 0)      asm volatile("s_waitcnt vmcnt(0)" ::: "memory");
    else if constexpr (N == 6) asm volatile("s_waitcnt vmcnt(6)" ::: "memory");
    else if constexpr (N == 8) asm volatile("s_waitcnt vmcnt(8)" ::: "memory");
}

// ---------------- fp32 -> bf16 bulk convert (8 elems/thread) ----------------
__global__ void cvt_f32_bf16(const float* __restrict__ in,
                             ushort_t* __restrict__ out) {
    int i = blockIdx.x * 256 + threadIdx.x;
    const float4* p = (const float4*)in + (size_t)i * 2;
    float4 a = p[0], b = p[1];
    ushort8 r;
    r[0] = f2bf(a.x); r[1] = f2bf(a.y); r[2] = f2bf(a.z); r[3] = f2bf(a.w);
    r[4] = f2bf(b.x); r[5] = f2bf(b.y); r[6] = f2bf(b.z); r[7] = f2bf(b.w);
    *(ushort8*)(out + (size_t)i * 8) = r;
}

// ------------- transpose fp32 -> bf16: in[R][Cc] -> out[Cc][R] -------------
__global__ void transpose_f2b(const float* __restrict__ in,
                              ushort_t* __restrict__ out, int R, int Cc) {
    __shared__ ushort_t tile[32][33];
    int bx = blockIdx.x * 32;
    int by = blockIdx.y * 32;
    int tx = threadIdx.x & 31, ty = threadIdx.x >> 5;
    #pragma unroll
    for (int i = 0; i < 4; i++) {
        int r = ty * 4 + i;
        tile[r][tx] = f2bf(in[(size_t)(by + r) * Cc + bx + tx]);
    }
    __syncthreads();
    #pragma unroll
    for (int i = 0; i < 4; i++) {
        int r = ty * 4 + i;
        out[(size_t)(bx + r) * R + by + tx] = tile[tx][r];
    }
}

// ---------------- rope table: tab[t*32+j] = (cos, sin) ----------------
__global__ void rope_table(float2* __restrict__ tab) {
    int i = blockIdx.x * 256 + threadIdx.x;   // 65536 total
    int t = i >> 5, j = i & 31;
    float inv = exp2f((float)j * -0.41524101186092029f);
    float theta = (float)t * inv;
    float s, c;
    sincosf(theta, &s, &c);
    tab[i] = make_float2(c, s);
}

// ------- V transpose: Vb[bh][t][d] -> VbT[bh][d][t], 64x64 tiles -------
__global__ void vtrans(const ushort_t* __restrict__ Vb,
                       ushort_t* __restrict__ VbT) {
    __shared__ ushort_t tile[64 * 72];
    const int bh = blockIdx.y;
    const int t0 = blockIdx.x * 64;
    const int tid = threadIdx.x;
    const int r = tid >> 2, c = (tid & 3) * 16;
    const size_t base = (size_t)bh * (TT * HD);
    const ushort_t* g = Vb + base + (size_t)(t0 + r) * HD + c;
    *(ushort8*)&tile[r * 72 + c]     = *(const ushort8*)g;
    *(ushort8*)&tile[r * 72 + c + 8] = *(const ushort8*)(g + 8);
    __syncthreads();
    ushort8 a, b;
    #pragma unroll
    for (int j = 0; j < 8; j++) a[j] = tile[(c + j) * 72 + r];
    #pragma unroll
    for (int j = 0; j < 8; j++) b[j] = tile[(c + 8 + j) * 72 + r];
    ushort_t* o = VbT + base + (size_t)r * TT + t0 + c;
    *(ushort8*)o = a;
    *(ushort8*)(o + 8) = b;
}

// ---------------- GEMM: C = A * Bt^T  (A,Bt bf16) --------------------------
// 128x256 tile, BK=64, 512 threads = 8 waves (2M x 4N), double-buffered LDS,
// counted vmcnt (T3+T4), XOR-swizzled LDS via pre-swizzled global source
// (T2, rule-21 both-sides), setprio around MFMA cluster (T5), XCD-bijective
// block swizzle (T1).
// MODE 1: A=[M][Kd] row-major; qkv epilogue: rope q,k (q pre-scaled by
//         scale*log2e); scatter to [B*NH][T][HD]
// MODE 2: A head-major [(b*16+h)*2048+t][64]; fp32 store to CoutF[M][N]
template <int MODE, int BM>
__global__ __launch_bounds__(512, 2) void gemm_bt(
    const ushort_t* __restrict__ A, const ushort_t* __restrict__ Bt,
    float* __restrict__ CoutF,
    ushort_t* __restrict__ Qb, ushort_t* __restrict__ Kb, ushort_t* __restrict__ Vb,
    const float2* __restrict__ rope, int M, int N, int Kd) {
    constexpr int MR = BM / 32;      // M fragment repeats per wave (BM/2/16)
    constexpr int AL = BM / 64;      // A gl2lds per wave per K-tile
    constexpr int L  = AL + 4;       // vmem loads per STAGE per thread
    constexpr int NK = CC / 64;      // K-tiles (Kd == 1024 for both GEMMs)
    (void)M;

    __shared__ __attribute__((aligned(16))) ushort_t As[2][BM * 64];
    __shared__ __attribute__((aligned(16))) ushort_t Bs[2][256 * 64];

    const int tid = threadIdx.x;
    const int w = tid >> 6, l = tid & 63;
    const int lane15 = l & 15, quad = l >> 4;
    const int wm = (w >> 2) * (BM / 2);      // wave M offset (0 or BM/2)
    const int wn = (w & 3) * 64;             // wave N offset

    // XCD-aware bijective swizzle (both grids are multiples of 8 blocks)
    const int nbn = gridDim.x;
    const int nwg = nbn * gridDim.y;
    const int lid = blockIdx.y * nbn + blockIdx.x;
    const int sid = (lid & 7) * (nwg >> 3) + (lid >> 3);
    const int bn = sid % nbn, bm = sid / nbn;

    const int sr8 = l >> 3;      // staged row within 8-row block
    const int sc  = l & 7;       // 16B slot within 128B row

    // stage one K-tile (A: BM x 64, B: 256 x 64) into buffer `buf`.
    // LDS dest linear; source column slot XOR'd by row&7 so that a read of
    // LDS[row][cb ^ ((row&7)<<4)] returns G[row][cb]  (involution).
    auto STAGE = [&](int buf, int k0) {
        #pragma unroll
        for (int i = 0; i < AL; ++i) {
            int r = w * (BM / 8) + i * 8 + sr8;       // r&7 == sr8
            int gr = bm * BM + r;
            size_t e;
            if constexpr (MODE == 2)
                e = ((size_t)(gr >> 11)) * 2097152 + ((size_t)(k0 >> 6)) * 131072
                    + (size_t)(gr & (TT - 1)) * 64;
            else
                e = (size_t)gr * Kd + k0;
            const char* g = (const char*)(A + e) + ((sc ^ sr8) * 16);
            gl2lds16(g, (char*)&As[buf][0] + (w * (BM / 8) + i * 8) * 128);
        }
        #pragma unroll
        for (int i = 0; i < 4; ++i) {
            int r = w * 32 + i * 8 + sr8;
            int gr = bn * 256 + r;
            const char* g = (const char*)(Bt + (size_t)gr * Kd + k0)
                            + ((sc ^ sr8) * 16);
            gl2lds16(g, (char*)&Bs[buf][0] + (w * 32 + i * 8) * 128);
        }
    };

    f32x4 acc[MR][4];
    #pragma unroll
    for (int m = 0; m < MR; ++m)
        #pragma unroll
        for (int n = 0; n < 4; ++n)
            acc[m][n] = f32x4{0.f, 0.f, 0.f, 0.f};

    // prologue: tiles 0 and 1 in flight; wait tile 0 only
    STAGE(0, 0);
    STAGE(1, 64);
    waitvm<L>();
    __builtin_amdgcn_s_barrier();
    asm volatile("" ::: "memory");

    const int swz = (lane15 & 7) << 4;   // read-side XOR (row&7 == lane15&7)

    for (int k = 0; k < NK; ++k) {
        const char* Asb = (const char*)&As[k & 1][0];
        const char* Bsb = (const char*)&Bs[k & 1][0];
        #pragma unroll
        for (int kk = 0; kk < 2; ++kk) {
            const int cb = (kk * 64 + quad * 16) ^ swz;
            bf16x8 bfr[4];
            #pragma unroll
            for (int n = 0; n < 4; ++n)
                bfr[n] = *(const bf16x8*)(Bsb + (wn + n * 16 + lane15) * 128 + cb);
            bf16x8 af[MR];
            #pragma unroll
            for (int m = 0; m < MR; ++m)
                af[m] = *(const bf16x8*)(Asb + (wm + m * 16 + lane15) * 128 + cb);
            __builtin_amdgcn_s_setprio(1);
            #pragma unroll
            for (int m = 0; m < MR; ++m)
                #pragma unroll
                for (int n = 0; n < 4; ++n)
                    acc[m][n] = __builtin_amdgcn_mfma_f32_16x16x32_bf16(
                        af[m], bfr[n], acc[m][n], 0, 0, 0);
            __builtin_amdgcn_s_setprio(0);
        }
        if (k == NK - 1) break;

        // release buf[k&1]: MFMAs must not sink past, reads must be retired
        __builtin_amdgcn_sched_barrier(0);
        asm volatile("s_waitcnt lgkmcnt(0)" ::: "memory");
        __builtin_amdgcn_s_barrier();
        asm volatile("" ::: "memory");
        // stage k+2 into just-released buffer; wait k+1 complete (counted,
        // leaves k+2's L loads in flight across the barrier)
        if (k + 2 < NK) { STAGE(k & 1, (k + 2) * 64); waitvm<L>(); }
        else            waitvm<0>();
        __builtin_amdgcn_s_barrier();
        asm volatile("" ::: "memory");
    }

    if constexpr (MODE == 1) {
        const float SCQ = 0.125f * 1.4426950408889634f;   // folded into Q
        const int colbase = bn * 256 + wn;          // multiple of 64
        const int seg = colbase >> 10;              // 0=q 1=k 2=v
        const int h = (colbase & 1023) >> 6;        // head
        #pragma unroll
        for (int m = 0; m < MR; ++m) {
            int row0 = bm * BM + wm + m * 16 + quad * 4;
            #pragma unroll
            for (int r = 0; r < 4; ++r) {
                int row = row0 + r;
                int b = row >> 11, t = row & (TT - 1);
                size_t ob = ((size_t)(b * NH + h) * TT + t) * HD;
                if (seg == 2) {
                    #pragma unroll
                    for (int n = 0; n < 4; ++n)
                        Vb[ob + n * 16 + lane15] = f2bf(acc[m][n][r]);
                } else {
                    ushort_t* dst = (seg == 0) ? Qb : Kb;
                    #pragma unroll
                    for (int n = 0; n < 2; ++n) {
                        int j = n * 16 + lane15;        // 0..31
                        float2 cs = rope[t * 32 + j];
                        float x1 = acc[m][n][r];        // d = j
                        float x2 = acc[m][n + 2][r];    // d = j+32
                        float y1 = x1 * cs.x - x2 * cs.y;
                        float y2 = x2 * cs.x + x1 * cs.y;
                        if (seg == 0) { y1 *= SCQ; y2 *= SCQ; }
                        dst[ob + j]      = f2bf(y1);
                        dst[ob + 32 + j] = f2bf(y2);
                    }
                }
            }
        }
    } else {
        #pragma unroll
        for (int m = 0; m < MR; ++m) {
            #pragma unroll
            for (int r = 0; r < 4; ++r) {
                size_t rb = (size_t)(bm * BM + wm + m * 16 + quad * 4 + r) * N
                            + bn * 256 + wn;
                #pragma unroll
                for (int n = 0; n < 4; ++n)
                    CoutF[rb + n * 16 + lane15] = acc[m][n][r];
            }
        }
    }
}

// ---------------- flash attention (causal), O in place over Q --------------
// grid: (16 q-tiles, B*NH) = 1024 blocks -> 4 blocks/CU (2x occupancy vs
// paired scheme). Longest q-tile first (qt = 15 - x); XCD-clustered remap
// puts all 16 blocks of a head on one XCD's L2 (K/V reuse).
// S^T = K*Q^T: S^T's C-frag (kcol=quad*4+reg, qrow=lane15) IS the A-operand
// layout of mfma_16x16x16_bf16 -> P never touches LDS. Q pre-scaled by
// scale*log2e in GEMM1, so scores are already in the exp2 domain.
// Defer-max (T13, THR=8): skip O-rescale while the running max grows <= 8
// (exp2-domain); P bounded by 2^8, f32 accumulators absorb it.
__global__ __launch_bounds__(512, 4) void attn_kernel(
    ushort_t* __restrict__ Qb, const ushort_t* __restrict__ Kb,
    const ushort_t* __restrict__ VbT) {
    __shared__ __attribute__((aligned(16))) ushort_t Ks[64 * 72];   // K tile [t][d]
    __shared__ __attribute__((aligned(16))) ushort_t Vs[64 * 72];   // V^T tile [d][t]

    const int tid = threadIdx.x;
    const int w = tid >> 6, l = tid & 63;
    const int lane15 = l & 15, quad = l >> 4;

    // dispatch-order id -> (bh, qt): XCD d&7 owns heads [xcd*8, xcd*8+8);
    // within an XCD, qt descends so the longest blocks start first.
    const int d = blockIdx.y * gridDim.x + blockIdx.x;
    const int xcd = d & 7, j = d >> 3;
    const int bh = xcd * 8 + (j & 7);
    const int qt = 15 - (j >> 3);
    const size_t base = (size_t)bh * (TT * HD);

    const int sr = tid >> 3;         // staging row 0..63
    const int sd = (tid & 7) * 8;    // staging col (elems), 16B per thread
    const ushort_t* kgb = Kb  + base + (size_t)sr * HD + sd;   // + kt*64*HD
    const ushort_t* vgb = VbT + base + (size_t)sr * TT + sd;   // + kt*64

    const int q0 = qt * 128;
    const int rbase = q0 + w * 16;     // wave owns 16 q-rows
    const int ktmax = 2 * qt + 1;

    // Q fragments (B-operand of S^T: n=lane15->qrow, k=quad*8+j->dim)
    bf16x8 qf0, qf1;
    {
        const ushort_t* qp = Qb + base + (size_t)(rbase + lane15) * HD + quad * 8;
        qf0 = *(const bf16x8*)qp;
        qf1 = *(const bf16x8*)(qp + 32);
    }

    f32x4 o[4];
    #pragma unroll
    for (int nt = 0; nt < 4; nt++) o[nt] = f32x4{0.f, 0.f, 0.f, 0.f};
    float mrow = -INFINITY, lrow = 0.f;   // per qrow=lane15

    // prefetch tile 0
    ushort8 kr = *(const ushort8*)kgb;
    ushort8 vr = *(const ushort8*)vgb;

    for (int kt = 0; kt <= ktmax; kt++) {
        __syncthreads();   // prior iter's LDS readers done
        *(ushort8*)&Ks[sr * 72 + sd] = kr;
        *(ushort8*)&Vs[sr * 72 + sd] = vr;
        __syncthreads();
        if (kt < ktmax) {   // prefetch next tile; overlaps compute
            kr = *(const ushort8*)(kgb + (size_t)(kt + 1) * 64 * HD);
            vr = *(const ushort8*)(vgb + (size_t)(kt + 1) * 64);
        }

        // waves 0-3's last tile is fully causally masked: skip compute
        // (wave-uniform; barriers stay outside this guard)
        if (kt * 64 > rbase + 15) continue;

        // S^T tiles: D[kcol][qrow], kcol=c*16+quad*4+reg, qrow=lane15
        f32x4 s[4];
        #pragma unroll
        for (int c = 0; c < 4; c++) {
            bf16x8 k0 = *(const bf16x8*)&Ks[(c * 16 + lane15) * 72 + quad * 8];
            bf16x8 k1 = *(const bf16x8*)&Ks[(c * 16 + lane15) * 72 + 32 + quad * 8];
            f32x4 z = f32x4{0.f, 0.f, 0.f, 0.f};
            z = __builtin_amdgcn_mfma_f32_16x16x32_bf16(k0, qf0, z, 0, 0, 0);
            s[c] = __builtin_amdgcn_mfma_f32_16x16x32_bf16(k1, qf1, z, 0, 0, 0);
        }

        const int qrow = rbase + lane15;
        if (kt * 64 + 63 > rbase) {   // masking needed (wave-uniform)
            #pragma unroll
            for (int c = 0; c < 4; c++)
                #pragma unroll
                for (int r = 0; r < 4; r++)
                    if (kt * 64 + c * 16 + quad * 4 + r > qrow) s[c][r] = -1e9f;
        }

        // per-qrow max: 16 in-lane + cross-quad (2 shuffles)
        float mt = s[0][0];
        #pragma unroll
        for (int c = 0; c < 4; c++)
            #pragma unroll
            for (int r = 0; r < 4; r++) mt = fmaxf(mt, s[c][r]);
        mt = fmaxf(mt, __shfl_xor(mt, 16, 64));
        mt = fmaxf(mt, __shfl_xor(mt, 32, 64));

        // defer-max: rescale only when the max grew by > 8 (exp2 domain)
        float alpha = 1.0f;
        if (!__all(mt - mrow <= 8.0f)) {
            float mn = fmaxf(mrow, mt);
            alpha = __builtin_amdgcn_exp2f(mrow - mn);
            mrow = mn;
            // alpha lives in lane=qrow (replicated across quads); o rows are
            // qrow = rbase + quad*4 + r -> broadcast from lane quad*4+r
            #pragma unroll
            for (int r = 0; r < 4; r++) {
                float aO = __shfl(alpha, quad * 4 + r, 64);
                #pragma unroll
                for (int nt = 0; nt < 4; nt++) o[nt][r] *= aO;
            }
        }

        #pragma unroll
        for (int c = 0; c < 4; c++)
            #pragma unroll
            for (int r = 0; r < 4; r++)
                s[c][r] = __builtin_amdgcn_exp2f(s[c][r] - mrow);

        float rs = 0.f;
        #pragma unroll
        for (int c = 0; c < 4; c++)
            rs += (s[c][0] + s[c][1]) + (s[c][2] + s[c][3]);
        rs += __shfl_xor(rs, 16, 64);
        rs += __shfl_xor(rs, 32, 64);
        lrow = lrow * alpha + rs;

        // P A-frags (m=lane15->qrow, k=quad*4+j->kcol) == S^T C-frag
        #pragma unroll
        for (int c = 0; c < 4; c++) {
            s16x4 pf;
            #pragma unroll
            for (int r = 0; r < 4; r++) pf[r] = (short)f2bf(s[c][r]);
            #pragma unroll
            for (int nt = 0; nt < 4; nt++) {
                s16x4 vf = *(const s16x4*)&Vs[(nt * 16 + lane15) * 72 +
                                              c * 16 + quad * 4];
                o[nt] = __builtin_amdgcn_mfma_f32_16x16x16bf16_1k(
                    pf, vf, o[nt], 0, 0, 0);
            }
        }
    }

    // epilogue: O in place over this wave's Q rows (head-major)
    float linv = 1.0f / lrow;   // lane=qrow domain
    #pragma unroll
    for (int r = 0; r < 4; r++) {
        float lO = __shfl(linv, quad * 4 + r, 64);
        size_t rb = base + (size_t)(rbase + quad * 4 + r) * HD;
        #pragma unroll
        for (int nt = 0; nt < 4; nt++)
            Qb[rb + nt * 16 + lane15] = f2bf(o[nt][r] * lO);
    }
}

// ---------------- launch ----------------
extern "C" void kernel_launch(void* const* d_in, const int* in_sizes, int n_in,
                              void* d_out, int out_size, void* d_ws, size_t ws_size,
                              hipStream_t stream) {
    const float* x    = (const float*)d_in[0];   // [8192][1024] fp32
    const float* wqkv = (const float*)d_in[1];   // [1024][3072] fp32
    const float* wout = (const float*)d_in[2];   // [1024][1024] fp32
    float* out = (float*)d_out;                  // [8192][1024] fp32

    // ws layout (72.5 MiB total):
    char* ws = (char*)d_ws;
    ushort_t* WqkvT = (ushort_t*)(ws);                        // [3072][1024] bf16
    ushort_t* WoutT = (ushort_t*)(ws + 6291456);              // [1024][1024] bf16
    float2*   rope  = (float2*)  (ws + 8388608);              // [2048*32]
    ushort_t* Xb    = (ushort_t*)(ws + 8912896);              // [8192][1024] bf16
    ushort_t* Qb    = (ushort_t*)(ws + 8912896 + 16777216);   // [64][2048][64]
    ushort_t* Kb    = (ushort_t*)(ws + 8912896 + 2 * 16777216);
    ushort_t* Vb    = (ushort_t*)(ws + 8912896 + 3 * 16777216);
    // VbT aliases Xb: Xb is dead after GEMM1, VbT produced after GEMM1.
    ushort_t* VbT   = Xb;                                     // [64][64][2048]

    cvt_f32_bf16<<<dim3(MM * CC / (256 * 8)), 256, 0, stream>>>(x, Xb);
    transpose_f2b<<<dim3(3 * CC / 32, CC / 32), 256, 0, stream>>>(wqkv, WqkvT, CC, 3 * CC);
    transpose_f2b<<<dim3(CC / 32, CC / 32), 256, 0, stream>>>(wout, WoutT, CC, CC);
    rope_table<<<dim3(256), 256, 0, stream>>>(rope);

    // 128x256 tiles: grid1 = 12x64 = 768 blocks (3 exact CU-rounds),
    // grid2 = 4x64 = 256 blocks (1 exact round); both %8==0 for XCD swizzle.
    gemm_bt<1, 128><<<dim3(3 * CC / 256, MM / 128), 512, 0, stream>>>(
        Xb, WqkvT, nullptr, Qb, Kb, Vb, rope, MM, 3 * CC, CC);

    vtrans<<<dim3(TT / 64, BB * NH), 256, 0, stream>>>(Vb, VbT);

    attn_kernel<<<dim3(16, BB * NH), 512, 0, stream>>>(Qb, Kb, VbT);

    gemm_bt<2, 128><<<dim3(CC / 256, MM / 128), 512, 0, stream>>>(
        Qb, WoutT, out, nullptr, nullptr, nullptr, nullptr, MM, CC, CC);
}

// Round 3
// 264.426 us; speedup vs baseline: 1.0631x; 1.0242x over previous
//
#include <hip/hip_runtime.h>
#include <stdint.h>

#define DEVI __device__ __forceinline__

typedef unsigned short ushort_t;
typedef __bf16 bf16x8 __attribute__((ext_vector_type(8)));
typedef float f32x4 __attribute__((ext_vector_type(4)));
typedef unsigned short ushort8 __attribute__((ext_vector_type(8)));
typedef short s16x4 __attribute__((ext_vector_type(4)));

// ---- constants ----
#define BB 4
#define TT 2048
#define CC 1024
#define NH 16
#define HD 64
#define MM (BB*TT)          // 8192

// native RNE f32->bf16 (compiler pairs into v_cvt_pk_bf16_f32; m240)
DEVI ushort_t f2bf(float f) {
    __bf16 h = (__bf16)f;
    return __builtin_bit_cast(ushort_t, h);
}

typedef const __attribute__((address_space(1))) unsigned int guint_t;
typedef __attribute__((address_space(3))) unsigned int luint_t;

// async global->LDS, 16B/lane; lds dest is wave-uniform base + lane*16
DEVI void gl2lds16(const void* g, void* lds) {
    __builtin_amdgcn_global_load_lds((guint_t*)(uintptr_t)g,
                                     (luint_t*)(unsigned int)(uintptr_t)lds,
                                     16, 0, 0);
}

template <int N> DEVI void waitvm() {
    static_assert(N == 0 || N == 6 || N == 8, "unsupported vmcnt literal");
    if constexpr (N == 0)      asm volatile("s_waitcnt vmcnt(0)" ::: "memory");
    else if constexpr (N == 6) asm volatile("s_waitcnt vmcnt(6)" ::: "memory");
    else if constexpr (N == 8) asm volatile("s_waitcnt vmcnt(8)" ::: "memory");
}

// ---------------- fp32 -> bf16 bulk convert (8 elems/thread) ----------------
__global__ void cvt_f32_bf16(const float* __restrict__ in,
                             ushort_t* __restrict__ out) {
    int i = blockIdx.x * 256 + threadIdx.x;
    const float4* p = (const float4*)in + (size_t)i * 2;
    float4 a = p[0], b = p[1];
    ushort8 r;
    r[0] = f2bf(a.x); r[1] = f2bf(a.y); r[2] = f2bf(a.z); r[3] = f2bf(a.w);
    r[4] = f2bf(b.x); r[5] = f2bf(b.y); r[6] = f2bf(b.z); r[7] = f2bf(b.w);
    *(ushort8*)(out + (size_t)i * 8) = r;
}

// ------------- transpose fp32 -> bf16: in[R][Cc] -> out[Cc][R] -------------
__global__ void transpose_f2b(const float* __restrict__ in,
                              ushort_t* __restrict__ out, int R, int Cc) {
    __shared__ ushort_t tile[32][33];
    int bx = blockIdx.x * 32;
    int by = blockIdx.y * 32;
    int tx = threadIdx.x & 31, ty = threadIdx.x >> 5;
    #pragma unroll
    for (int i = 0; i < 4; i++) {
        int r = ty * 4 + i;
        tile[r][tx] = f2bf(in[(size_t)(by + r) * Cc + bx + tx]);
    }
    __syncthreads();
    #pragma unroll
    for (int i = 0; i < 4; i++) {
        int r = ty * 4 + i;
        out[(size_t)(bx + r) * R + by + tx] = tile[tx][r];
    }
}

// ---------------- rope table: tab[t*32+j] = (cos, sin) ----------------
__global__ void rope_table(float2* __restrict__ tab) {
    int i = blockIdx.x * 256 + threadIdx.x;   // 65536 total
    int t = i >> 5, j = i & 31;
    float inv = exp2f((float)j * -0.41524101186092029f);
    float theta = (float)t * inv;
    float s, c;
    sincosf(theta, &s, &c);
    tab[i] = make_float2(c, s);
}

// ------- V transpose: Vb[bh][t][d] -> VbT[bh][d][t], 64x64 tiles -------
__global__ void vtrans(const ushort_t* __restrict__ Vb,
                       ushort_t* __restrict__ VbT) {
    __shared__ ushort_t tile[64 * 72];
    const int bh = blockIdx.y;
    const int t0 = blockIdx.x * 64;
    const int tid = threadIdx.x;
    const int r = tid >> 2, c = (tid & 3) * 16;
    const size_t base = (size_t)bh * (TT * HD);
    const ushort_t* g = Vb + base + (size_t)(t0 + r) * HD + c;
    *(ushort8*)&tile[r * 72 + c]     = *(const ushort8*)g;
    *(ushort8*)&tile[r * 72 + c + 8] = *(const ushort8*)(g + 8);
    __syncthreads();
    ushort8 a, b;
    #pragma unroll
    for (int j = 0; j < 8; j++) a[j] = tile[(c + j) * 72 + r];
    #pragma unroll
    for (int j = 0; j < 8; j++) b[j] = tile[(c + 8 + j) * 72 + r];
    ushort_t* o = VbT + base + (size_t)r * TT + t0 + c;
    *(ushort8*)o = a;
    *(ushort8*)(o + 8) = b;
}

// ---------------- GEMM: C = A * Bt^T  (A,Bt bf16) --------------------------
// 128x256 tile, BK=64, 512 threads = 8 waves (2M x 4N), double-buffered LDS,
// counted vmcnt (T3+T4), XOR-swizzled LDS via pre-swizzled global source
// (T2, rule-21 both-sides), setprio around MFMA cluster (T5), XCD-bijective
// block swizzle (T1).
// MODE 1: A=[M][Kd] row-major; qkv epilogue: rope q,k (q pre-scaled by
//         scale*log2e); scatter to [B*NH][T][HD]
// MODE 2: A head-major [(b*16+h)*2048+t][64]; fp32 store to CoutF[M][N]
template <int MODE, int BM>
__global__ __launch_bounds__(512, 2) void gemm_bt(
    const ushort_t* __restrict__ A, const ushort_t* __restrict__ Bt,
    float* __restrict__ CoutF,
    ushort_t* __restrict__ Qb, ushort_t* __restrict__ Kb, ushort_t* __restrict__ Vb,
    const float2* __restrict__ rope, int M, int N, int Kd) {
    constexpr int MR = BM / 32;      // M fragment repeats per wave (BM/2/16)
    constexpr int AL = BM / 64;      // A gl2lds per wave per K-tile
    constexpr int L  = AL + 4;       // vmem loads per STAGE per thread
    constexpr int NK = CC / 64;      // K-tiles (Kd == 1024 for both GEMMs)
    (void)M;

    __shared__ __attribute__((aligned(16))) ushort_t As[2][BM * 64];
    __shared__ __attribute__((aligned(16))) ushort_t Bs[2][256 * 64];

    const int tid = threadIdx.x;
    const int w = tid >> 6, l = tid & 63;
    const int lane15 = l & 15, quad = l >> 4;
    const int wm = (w >> 2) * (BM / 2);      // wave M offset (0 or BM/2)
    const int wn = (w & 3) * 64;             // wave N offset

    // XCD-aware bijective swizzle (both grids are multiples of 8 blocks)
    const int nbn = gridDim.x;
    const int nwg = nbn * gridDim.y;
    const int lid = blockIdx.y * nbn + blockIdx.x;
    const int sid = (lid & 7) * (nwg >> 3) + (lid >> 3);
    const int bn = sid % nbn, bm = sid / nbn;

    const int sr8 = l >> 3;      // staged row within 8-row block
    const int sc  = l & 7;       // 16B slot within 128B row

    // stage one K-tile (A: BM x 64, B: 256 x 64) into buffer `buf`.
    // LDS dest linear; source column slot XOR'd by row&7 so that a read of
    // LDS[row][cb ^ ((row&7)<<4)] returns G[row][cb]  (involution).
    auto STAGE = [&](int buf, int k0) {
        #pragma unroll
        for (int i = 0; i < AL; ++i) {
            int r = w * (BM / 8) + i * 8 + sr8;       // r&7 == sr8
            int gr = bm * BM + r;
            size_t e;
            if constexpr (MODE == 2)
                e = ((size_t)(gr >> 11)) * 2097152 + ((size_t)(k0 >> 6)) * 131072
                    + (size_t)(gr & (TT - 1)) * 64;
            else
                e = (size_t)gr * Kd + k0;
            const char* g = (const char*)(A + e) + ((sc ^ sr8) * 16);
            gl2lds16(g, (char*)&As[buf][0] + (w * (BM / 8) + i * 8) * 128);
        }
        #pragma unroll
        for (int i = 0; i < 4; ++i) {
            int r = w * 32 + i * 8 + sr8;
            int gr = bn * 256 + r;
            const char* g = (const char*)(Bt + (size_t)gr * Kd + k0)
                            + ((sc ^ sr8) * 16);
            gl2lds16(g, (char*)&Bs[buf][0] + (w * 32 + i * 8) * 128);
        }
    };

    f32x4 acc[MR][4];
    #pragma unroll
    for (int m = 0; m < MR; ++m)
        #pragma unroll
        for (int n = 0; n < 4; ++n)
            acc[m][n] = f32x4{0.f, 0.f, 0.f, 0.f};

    // prologue: tiles 0 and 1 in flight; wait tile 0 only
    STAGE(0, 0);
    STAGE(1, 64);
    waitvm<L>();
    __builtin_amdgcn_s_barrier();
    asm volatile("" ::: "memory");

    const int swz = (lane15 & 7) << 4;   // read-side XOR (row&7 == lane15&7)

    for (int k = 0; k < NK; ++k) {
        const char* Asb = (const char*)&As[k & 1][0];
        const char* Bsb = (const char*)&Bs[k & 1][0];
        #pragma unroll
        for (int kk = 0; kk < 2; ++kk) {
            const int cb = (kk * 64 + quad * 16) ^ swz;
            bf16x8 bfr[4];
            #pragma unroll
            for (int n = 0; n < 4; ++n)
                bfr[n] = *(const bf16x8*)(Bsb + (wn + n * 16 + lane15) * 128 + cb);
            bf16x8 af[MR];
            #pragma unroll
            for (int m = 0; m < MR; ++m)
                af[m] = *(const bf16x8*)(Asb + (wm + m * 16 + lane15) * 128 + cb);
            __builtin_amdgcn_s_setprio(1);
            #pragma unroll
            for (int m = 0; m < MR; ++m)
                #pragma unroll
                for (int n = 0; n < 4; ++n)
                    acc[m][n] = __builtin_amdgcn_mfma_f32_16x16x32_bf16(
                        af[m], bfr[n], acc[m][n], 0, 0, 0);
            __builtin_amdgcn_s_setprio(0);
        }
        if (k == NK - 1) break;

        // release buf[k&1]: MFMAs must not sink past, reads must be retired
        __builtin_amdgcn_sched_barrier(0);
        asm volatile("s_waitcnt lgkmcnt(0)" ::: "memory");
        __builtin_amdgcn_s_barrier();
        asm volatile("" ::: "memory");
        // stage k+2 into just-released buffer; wait k+1 complete (counted,
        // leaves k+2's L loads in flight across the barrier)
        if (k + 2 < NK) { STAGE(k & 1, (k + 2) * 64); waitvm<L>(); }
        else            waitvm<0>();
        __builtin_amdgcn_s_barrier();
        asm volatile("" ::: "memory");
    }

    if constexpr (MODE == 1) {
        const float SCQ = 0.125f * 1.4426950408889634f;   // folded into Q
        const int colbase = bn * 256 + wn;          // multiple of 64
        const int seg = colbase >> 10;              // 0=q 1=k 2=v
        const int h = (colbase & 1023) >> 6;        // head
        #pragma unroll
        for (int m = 0; m < MR; ++m) {
            int row0 = bm * BM + wm + m * 16 + quad * 4;
            #pragma unroll
            for (int r = 0; r < 4; ++r) {
                int row = row0 + r;
                int b = row >> 11, t = row & (TT - 1);
                size_t ob = ((size_t)(b * NH + h) * TT + t) * HD;
                if (seg == 2) {
                    #pragma unroll
                    for (int n = 0; n < 4; ++n)
                        Vb[ob + n * 16 + lane15] = f2bf(acc[m][n][r]);
                } else {
                    ushort_t* dst = (seg == 0) ? Qb : Kb;
                    #pragma unroll
                    for (int n = 0; n < 2; ++n) {
                        int j = n * 16 + lane15;        // 0..31
                        float2 cs = rope[t * 32 + j];
                        float x1 = acc[m][n][r];        // d = j
                        float x2 = acc[m][n + 2][r];    // d = j+32
                        float y1 = x1 * cs.x - x2 * cs.y;
                        float y2 = x2 * cs.x + x1 * cs.y;
                        if (seg == 0) { y1 *= SCQ; y2 *= SCQ; }
                        dst[ob + j]      = f2bf(y1);
                        dst[ob + 32 + j] = f2bf(y2);
                    }
                }
            }
        }
    } else {
        #pragma unroll
        for (int m = 0; m < MR; ++m) {
            #pragma unroll
            for (int r = 0; r < 4; ++r) {
                size_t rb = (size_t)(bm * BM + wm + m * 16 + quad * 4 + r) * N
                            + bn * 256 + wn;
                #pragma unroll
                for (int n = 0; n < 4; ++n)
                    CoutF[rb + n * 16 + lane15] = acc[m][n][r];
            }
        }
    }
}

// ---------------- flash attention (causal), O in place over Q --------------
// grid: (16 q-tiles, B*NH) = 1024 blocks, all co-resident (4/CU).
// XCD-clustered remap: XCD d&7 owns heads [xcd*8, xcd*8+8) (K/V L2 reuse,
// proven -4.4x FETCH). qt permuted via nibble table so stride-32 CU-cohorts
// {p[x],p[x+4],p[x+8],p[x+12]} each sum to 30 -> balanced per-CU work.
// S^T = K*Q^T: S^T's C-frag (kcol=quad*4+reg, qrow=lane15) IS the A-operand
// layout of mfma_16x16x16_bf16 -> P never touches LDS. Q pre-scaled by
// scale*log2e in GEMM1, so scores are already in the exp2 domain.
// Shuffle-free steady state: defer-max checked on IN-LANE partial max only
// (exact as a bound test); row-sum l via ones-column MFMA (C-frag domain,
// same layout as o -> epilogue needs no broadcast). Single barrier per
// k-tile via double-buffered K/V LDS.
__global__ __launch_bounds__(512, 4) void attn_kernel(
    ushort_t* __restrict__ Qb, const ushort_t* __restrict__ Kb,
    const ushort_t* __restrict__ VbT) {
    __shared__ __attribute__((aligned(16))) ushort_t Ks[2][64 * 72]; // K [t][d]
    __shared__ __attribute__((aligned(16))) ushort_t Vs[2][64 * 72]; // V^T [d][t]

    const int tid = threadIdx.x;
    const int w = tid >> 6, l = tid & 63;
    const int lane15 = l & 15, quad = l >> 4;

    const int d = blockIdx.y * gridDim.x + blockIdx.x;
    const int xcd = d & 7, j = d >> 3;
    const int bh = xcd * 8 + (j & 7);
    // qt perm: {15,14,13,12, 0,1,2,3, 11,10,9,8, 4,5,6,7} (nibbles, i=0 low)
    const int qt = (int)((0x765489AB3210CDEFull >> (4 * (j >> 3))) & 15);
    const size_t base = (size_t)bh * (TT * HD);

    const int sr = tid >> 3;         // staging row 0..63
    const int sd = (tid & 7) * 8;    // staging col (elems), 16B per thread
    const ushort_t* kgb = Kb  + base + (size_t)sr * HD + sd;   // + kt*64*HD
    const ushort_t* vgb = VbT + base + (size_t)sr * TT + sd;   // + kt*64

    const int q0 = qt * 128;
    const int rbase = q0 + w * 16;     // wave owns 16 q-rows
    const int ktmax = 2 * qt + 1;      // >= 1 always

    // Q fragments (B-operand of S^T: n=lane15->qrow, k=quad*8+j->dim)
    bf16x8 qf0, qf1;
    {
        const ushort_t* qp = Qb + base + (size_t)(rbase + lane15) * HD + quad * 8;
        qf0 = *(const bf16x8*)qp;
        qf1 = *(const bf16x8*)(qp + 32);
    }

    f32x4 o[4];
    #pragma unroll
    for (int nt = 0; nt < 4; nt++) o[nt] = f32x4{0.f, 0.f, 0.f, 0.f};
    f32x4 lacc = f32x4{0.f, 0.f, 0.f, 0.f};   // row-sum, C-frag domain
    float mrow = -INFINITY;                    // per qrow=lane15

    const s16x4 ONES = {(short)0x3F80, (short)0x3F80,
                        (short)0x3F80, (short)0x3F80};   // bf16 1.0 x4

    // prologue: tile 0 -> buf0; tile 1 -> regs
    ushort8 kr = *(const ushort8*)kgb;
    ushort8 vr = *(const ushort8*)vgb;
    *(ushort8*)&Ks[0][sr * 72 + sd] = kr;
    *(ushort8*)&Vs[0][sr * 72 + sd] = vr;
    kr = *(const ushort8*)(kgb + (size_t)64 * HD);
    vr = *(const ushort8*)(vgb + 64);
    __syncthreads();

    for (int kt = 0; kt <= ktmax; kt++) {
        const int buf = kt & 1;
        // at loop top kr/vr hold tile kt+1; write it to the other buffer
        // (its previous readers finished before the end-of-iter barrier)
        if (kt < ktmax) {
            *(ushort8*)&Ks[buf ^ 1][sr * 72 + sd] = kr;
            *(ushort8*)&Vs[buf ^ 1][sr * 72 + sd] = vr;
        }
        if (kt + 2 <= ktmax) {   // prefetch tile kt+2; overlaps compute
            kr = *(const ushort8*)(kgb + (size_t)(kt + 2) * 64 * HD);
            vr = *(const ushort8*)(vgb + (size_t)(kt + 2) * 64);
        }

        // waves 0-3's last tile can be fully causally masked: skip compute
        // (wave-uniform guard; the barrier below stays outside it)
        if (kt * 64 <= rbase + 15) {
            // S^T tiles: D[kcol][qrow], kcol=c*16+quad*4+reg, qrow=lane15
            f32x4 s[4];
            #pragma unroll
            for (int c = 0; c < 4; c++) {
                bf16x8 k0 = *(const bf16x8*)&Ks[buf][(c * 16 + lane15) * 72 + quad * 8];
                bf16x8 k1 = *(const bf16x8*)&Ks[buf][(c * 16 + lane15) * 72 + 32 + quad * 8];
                f32x4 z = f32x4{0.f, 0.f, 0.f, 0.f};
                z = __builtin_amdgcn_mfma_f32_16x16x32_bf16(k0, qf0, z, 0, 0, 0);
                s[c] = __builtin_amdgcn_mfma_f32_16x16x32_bf16(k1, qf1, z, 0, 0, 0);
            }

            const int qrow = rbase + lane15;
            if (kt * 64 + 63 > rbase) {   // masking needed (wave-uniform)
                #pragma unroll
                for (int c = 0; c < 4; c++)
                    #pragma unroll
                    for (int r = 0; r < 4; r++)
                        if (kt * 64 + c * 16 + quad * 4 + r > qrow) s[c][r] = -1e9f;
            }

            // in-lane partial max (v_max3 triples: 8 ops)
            float a0 = fmaxf(fmaxf(s[0][0], s[0][1]), s[0][2]);
            float a1 = fmaxf(fmaxf(s[0][3], s[1][0]), s[1][1]);
            float a2 = fmaxf(fmaxf(s[1][2], s[1][3]), s[2][0]);
            float a3 = fmaxf(fmaxf(s[2][1], s[2][2]), s[2][3]);
            float a4 = fmaxf(fmaxf(s[3][0], s[3][1]), s[3][2]);
            float mt = fmaxf(fmaxf(a0, a1), a2);
            mt = fmaxf(fmaxf(mt, a3), fmaxf(a4, s[3][3]));

            // defer-max: partial <= bound for all lanes  <=>  row max <= bound
            if (!__all(mt - mrow <= 8.0f)) {
                float mf = fmaxf(mt, __shfl_xor(mt, 16, 64));
                mf = fmaxf(mf, __shfl_xor(mf, 32, 64));
                float mn = fmaxf(mrow, mf);
                float alpha = __builtin_amdgcn_exp2f(mrow - mn);
                mrow = mn;
                #pragma unroll
                for (int r = 0; r < 4; r++) {
                    float aO = __shfl(alpha, quad * 4 + r, 64);
                    #pragma unroll
                    for (int nt = 0; nt < 4; nt++) o[nt][r] *= aO;
                    lacc[r] *= aO;
                }
            }

            // P A-frags (m->qrow, k=quad*4+j->kcol) == S^T C-frag; P bounded
            // by 2^8 (defer). l accumulates P via ones-column MFMA.
            #pragma unroll
            for (int c = 0; c < 4; c++) {
                s16x4 pf;
                #pragma unroll
                for (int r = 0; r < 4; r++)
                    pf[r] = (short)f2bf(__builtin_amdgcn_exp2f(s[c][r] - mrow));
                lacc = __builtin_amdgcn_mfma_f32_16x16x16bf16_1k(
                    pf, ONES, lacc, 0, 0, 0);
                #pragma unroll
                for (int nt = 0; nt < 4; nt++) {
                    s16x4 vf = *(const s16x4*)&Vs[buf][(nt * 16 + lane15) * 72 +
                                                      c * 16 + quad * 4];
                    o[nt] = __builtin_amdgcn_mfma_f32_16x16x16bf16_1k(
                        pf, vf, o[nt], 0, 0, 0);
                }
            }
        }

        if (kt < ktmax) __syncthreads();   // release buf^1 writers / buf readers
    }

    // epilogue: O in place over this wave's Q rows (head-major); l is in the
    // same C-frag domain as o -> no broadcast needed
    #pragma unroll
    for (int r = 0; r < 4; r++) {
        float lO = 1.0f / lacc[r];
        size_t rb = base + (size_t)(rbase + quad * 4 + r) * HD;
        #pragma unroll
        for (int nt = 0; nt < 4; nt++)
            Qb[rb + nt * 16 + lane15] = f2bf(o[nt][r] * lO);
    }
}

// ---------------- launch ----------------
extern "C" void kernel_launch(void* const* d_in, const int* in_sizes, int n_in,
                              void* d_out, int out_size, void* d_ws, size_t ws_size,
                              hipStream_t stream) {
    const float* x    = (const float*)d_in[0];   // [8192][1024] fp32
    const float* wqkv = (const float*)d_in[1];   // [1024][3072] fp32
    const float* wout = (const float*)d_in[2];   // [1024][1024] fp32
    float* out = (float*)d_out;                  // [8192][1024] fp32

    // ws layout (72.5 MiB total):
    char* ws = (char*)d_ws;
    ushort_t* WqkvT = (ushort_t*)(ws);                        // [3072][1024] bf16
    ushort_t* WoutT = (ushort_t*)(ws + 6291456);              // [1024][1024] bf16
    float2*   rope  = (float2*)  (ws + 8388608);              // [2048*32]
    ushort_t* Xb    = (ushort_t*)(ws + 8912896);              // [8192][1024] bf16
    ushort_t* Qb    = (ushort_t*)(ws + 8912896 + 16777216);   // [64][2048][64]
    ushort_t* Kb    = (ushort_t*)(ws + 8912896 + 2 * 16777216);
    ushort_t* Vb    = (ushort_t*)(ws + 8912896 + 3 * 16777216);
    // VbT aliases Xb: Xb is dead after GEMM1, VbT produced after GEMM1.
    ushort_t* VbT   = Xb;                                     // [64][64][2048]

    cvt_f32_bf16<<<dim3(MM * CC / (256 * 8)), 256, 0, stream>>>(x, Xb);
    transpose_f2b<<<dim3(3 * CC / 32, CC / 32), 256, 0, stream>>>(wqkv, WqkvT, CC, 3 * CC);
    transpose_f2b<<<dim3(CC / 32, CC / 32), 256, 0, stream>>>(wout, WoutT, CC, CC);
    rope_table<<<dim3(256), 256, 0, stream>>>(rope);

    // 128x256 tiles: grid1 = 12x64 = 768 blocks (3 exact CU-rounds),
    // grid2 = 4x64 = 256 blocks (1 exact round); both %8==0 for XCD swizzle.
    gemm_bt<1, 128><<<dim3(3 * CC / 256, MM / 128), 512, 0, stream>>>(
        Xb, WqkvT, nullptr, Qb, Kb, Vb, rope, MM, 3 * CC, CC);

    vtrans<<<dim3(TT / 64, BB * NH), 256, 0, stream>>>(Vb, VbT);

    attn_kernel<<<dim3(16, BB * NH), 512, 0, stream>>>(Qb, Kb, VbT);

    gemm_bt<2, 128><<<dim3(CC / 256, MM / 128), 512, 0, stream>>>(
        Qb, WoutT, out, nullptr, nullptr, nullptr, nullptr, MM, CC, CC);
}